// Round 1
// baseline (244.605 us; speedup 1.0000x reference)
//
#include <hip/hip_runtime.h>

#define BB 32
#define TT 1024
#define CC 384
#define MAXMEL 4096

// Per-batch inclusive scan of durations. One block (1024 threads) per batch.
// Writes cumsum to ws and (float)total to the tail of d_out.
__global__ __launch_bounds__(TT) void lr_scan_kernel(const int* __restrict__ dur,
                                                     int* __restrict__ cs,
                                                     float* __restrict__ out_total) {
    __shared__ int s[TT];
    const int b = blockIdx.x;
    const int tid = threadIdx.x;
    s[tid] = dur[b * TT + tid];
    __syncthreads();
    #pragma unroll
    for (int off = 1; off < TT; off <<= 1) {
        int v = (tid >= off) ? s[tid - off] : 0;
        __syncthreads();
        s[tid] += v;
        __syncthreads();
    }
    cs[b * TT + tid] = s[tid];
    if (tid == TT - 1) out_total[b] = (float)s[tid];
}

// Expansion: block = 256 threads = 8 frames x 32 lanes.
// Each frame-group binary-searches the LDS-cached cumsum row, then copies the
// 384-float token row as 3 float4 per lane (coalesced), or zeros if invalid.
__global__ __launch_bounds__(256) void lr_expand_kernel(const float* __restrict__ x,
                                                        const int* __restrict__ cs,
                                                        float* __restrict__ out) {
    __shared__ int s_cs[TT];
    const int b = blockIdx.y;
    const int chunk = blockIdx.x;
    const int tid = threadIdx.x;

    for (int j = tid; j < TT; j += 256) s_cs[j] = cs[b * TT + j];
    __syncthreads();

    const int total = s_cs[TT - 1];
    const int fsub = tid >> 5;
    const int lane = tid & 31;
    const int frame = chunk * 8 + fsub;

    float4* outp = (float4*)(out + ((size_t)b * MAXMEL + frame) * CC);

    if (frame < total) {
        // upper_bound: first idx with cs[idx] > frame  == searchsorted(side='right')
        int lo = 0, hi = TT;
        while (lo < hi) {
            int mid = (lo + hi) >> 1;
            if (s_cs[mid] <= frame) lo = mid + 1; else hi = mid;
        }
        const int tok = min(lo, TT - 1);
        const float4* src = (const float4*)(x + ((size_t)b * TT + tok) * CC);
        #pragma unroll
        for (int k = 0; k < 3; ++k) outp[lane + k * 32] = src[lane + k * 32];
    } else {
        const float4 z = make_float4(0.f, 0.f, 0.f, 0.f);
        #pragma unroll
        for (int k = 0; k < 3; ++k) outp[lane + k * 32] = z;
    }
}

extern "C" void kernel_launch(void* const* d_in, const int* in_sizes, int n_in,
                              void* d_out, int out_size, void* d_ws, size_t ws_size,
                              hipStream_t stream) {
    const float* x = (const float*)d_in[0];
    const int* dur = (const int*)d_in[1];  // int64 in reference -> int32 on device per harness
    float* out = (float*)d_out;
    int* cs = (int*)d_ws;  // 32*1024 ints = 128 KB scratch
    float* out_total = out + (size_t)BB * MAXMEL * CC;  // 32 floats at the tail

    lr_scan_kernel<<<BB, TT, 0, stream>>>(dur, cs, out_total);
    lr_expand_kernel<<<dim3(MAXMEL / 8, BB), 256, 0, stream>>>(x, cs, out);
}

// Round 3
// 244.581 us; speedup vs baseline: 1.0001x; 1.0001x over previous
//
#include <hip/hip_runtime.h>
#include <stdint.h>

#define BB 32
#define TT 1024
#define CC 384
#define MAXMEL 4096

// Shuffle-based inclusive scan of dur[b][0..1023] into s_cs; returns total.
__device__ __forceinline__ int block_scan_1024(const int* __restrict__ dur, int b,
                                               int* s_cs) {
    __shared__ int s_wsum[16];
    const int tid = threadIdx.x;
    const int lane = tid & 63;
    const int wid = tid >> 6;
    int v = dur[b * TT + tid];
    #pragma unroll
    for (int off = 1; off < 64; off <<= 1) {
        int n = __shfl_up(v, off, 64);
        if (lane >= off) v += n;
    }
    if (lane == 63) s_wsum[wid] = v;
    __syncthreads();
    if (wid == 0 && lane < 16) {
        int w = s_wsum[lane];
        #pragma unroll
        for (int off = 1; off < 16; off <<= 1) {
            int n = __shfl_up(w, off, 64);
            if (lane >= off) w += n;
        }
        s_wsum[lane] = w;
    }
    __syncthreads();
    if (wid > 0) v += s_wsum[wid - 1];
    s_cs[tid] = v;
    __syncthreads();
    return s_cs[TT - 1];
}

// ---------- Path A: tok precompute (u16, 256 KB ws) + streaming gather ----------

__global__ __launch_bounds__(1024) void lr_scan_tok16(const int* __restrict__ dur,
                                                      uint16_t* __restrict__ tok,
                                                      float* __restrict__ out_total) {
    __shared__ int s_cs[TT];
    const int b = blockIdx.x;
    const int tid = threadIdx.x;
    const int total = block_scan_1024(dur, b, s_cs);
    if (tid == 0) out_total[b] = (float)total;
    for (int f = tid; f < MAXMEL; f += 1024) {
        uint16_t t = 0xFFFFu;
        if (f < total) {
            int lo = 0, hi = TT;
            while (lo < hi) {
                int mid = (lo + hi) >> 1;
                if (s_cs[mid] <= f) lo = mid + 1; else hi = mid;
            }
            t = (uint16_t)min(lo, TT - 1);
        }
        tok[b * MAXMEL + f] = t;
    }
}

__global__ __launch_bounds__(256) void lr_expand_tok16(const float* __restrict__ x,
                                                       const uint16_t* __restrict__ tok,
                                                       float* __restrict__ out) {
    const int b = blockIdx.y;
    const int frame = blockIdx.x * 8 + (threadIdx.x >> 5);
    const int lane = threadIdx.x & 31;
    const uint32_t t = tok[b * MAXMEL + frame];
    float4* outp = (float4*)(out + ((size_t)b * MAXMEL + frame) * CC);
    if (t != 0xFFFFu) {
        const float4* src = (const float4*)(x + ((size_t)b * TT + t) * CC);
        #pragma unroll
        for (int k = 0; k < 3; ++k) outp[lane + k * 32] = src[lane + k * 32];
    } else {
        const float4 z = make_float4(0.f, 0.f, 0.f, 0.f);
        #pragma unroll
        for (int k = 0; k < 3; ++k) outp[lane + k * 32] = z;
    }
}

// ---------- Path B: cs only (128 KB ws, proven safe) + staged LDS search ----------

__global__ __launch_bounds__(1024) void lr_scan_cs(const int* __restrict__ dur,
                                                   int* __restrict__ cs,
                                                   float* __restrict__ out_total) {
    __shared__ int s_cs[TT];
    const int b = blockIdx.x;
    const int tid = threadIdx.x;
    const int total = block_scan_1024(dur, b, s_cs);
    cs[b * TT + tid] = s_cs[tid];
    if (tid == 0) out_total[b] = (float)total;
}

// 1024 threads = 64 frames x 16 lanes; 6 float4 per lane; cs staged once/block.
__global__ __launch_bounds__(1024) void lr_expand_search(const float* __restrict__ x,
                                                         const int* __restrict__ cs,
                                                         float* __restrict__ out) {
    __shared__ int s_cs[TT];
    const int b = blockIdx.y;
    const int tid = threadIdx.x;
    s_cs[tid] = cs[b * TT + tid];
    __syncthreads();
    const int total = s_cs[TT - 1];
    const int frame = blockIdx.x * 64 + (tid >> 4);
    const int lane = tid & 15;
    float4* outp = (float4*)(out + ((size_t)b * MAXMEL + frame) * CC);
    if (frame < total) {
        int lo = 0, hi = TT;
        while (lo < hi) {
            int mid = (lo + hi) >> 1;
            if (s_cs[mid] <= frame) lo = mid + 1; else hi = mid;
        }
        const int t = min(lo, TT - 1);
        const float4* src = (const float4*)(x + ((size_t)b * TT + t) * CC);
        #pragma unroll
        for (int k = 0; k < 6; ++k) outp[lane + k * 16] = src[lane + k * 16];
    } else {
        const float4 z = make_float4(0.f, 0.f, 0.f, 0.f);
        #pragma unroll
        for (int k = 0; k < 6; ++k) outp[lane + k * 16] = z;
    }
}

extern "C" void kernel_launch(void* const* d_in, const int* in_sizes, int n_in,
                              void* d_out, int out_size, void* d_ws, size_t ws_size,
                              hipStream_t stream) {
    const float* x = (const float*)d_in[0];
    const int* dur = (const int*)d_in[1];  // reference int64 -> int32 on device per harness
    float* out = (float*)d_out;
    float* out_total = out + (size_t)BB * MAXMEL * CC;  // 32 floats at the tail

    if (ws_size >= (size_t)BB * MAXMEL * sizeof(uint16_t)) {
        uint16_t* tok = (uint16_t*)d_ws;  // 256 KB
        lr_scan_tok16<<<BB, 1024, 0, stream>>>(dur, tok, out_total);
        lr_expand_tok16<<<dim3(MAXMEL / 8, BB), 256, 0, stream>>>(x, tok, out);
    } else {
        int* cs = (int*)d_ws;  // 128 KB
        lr_scan_cs<<<BB, 1024, 0, stream>>>(dur, cs, out_total);
        lr_expand_search<<<dim3(MAXMEL / 64, BB), 1024, 0, stream>>>(x, cs, out);
    }
}

// Round 5
// 239.953 us; speedup vs baseline: 1.0194x; 1.0193x over previous
//
#include <hip/hip_runtime.h>
#include <stdint.h>

#define BB 32
#define TT 1024
#define CC 384
#define MAXMEL 4096

typedef float f4 __attribute__((ext_vector_type(4)));  // native vec4 for nt builtins

// Shuffle-based inclusive scan of dur[b][0..1023] into s_cs; returns total.
__device__ __forceinline__ int block_scan_1024(const int* __restrict__ dur, int b,
                                               int* s_cs) {
    __shared__ int s_wsum[16];
    const int tid = threadIdx.x;
    const int lane = tid & 63;
    const int wid = tid >> 6;
    int v = dur[b * TT + tid];
    #pragma unroll
    for (int off = 1; off < 64; off <<= 1) {
        int n = __shfl_up(v, off, 64);
        if (lane >= off) v += n;
    }
    if (lane == 63) s_wsum[wid] = v;
    __syncthreads();
    if (wid == 0 && lane < 16) {
        int w = s_wsum[lane];
        #pragma unroll
        for (int off = 1; off < 16; off <<= 1) {
            int n = __shfl_up(w, off, 64);
            if (lane >= off) w += n;
        }
        s_wsum[lane] = w;
    }
    __syncthreads();
    if (wid > 0) v += s_wsum[wid - 1];
    s_cs[tid] = v;
    __syncthreads();
    return s_cs[TT - 1];
}

// ---------- Path A: tok precompute (u16, 256 KB ws) + streaming gather ----------

// Grid (4, BB): 4 blocks per batch, each redoes the cheap scan and searches
// 1024 frames (1 per thread) — 4x the occupancy of the single-block version.
__global__ __launch_bounds__(1024) void lr_scan_tok16(const int* __restrict__ dur,
                                                      uint16_t* __restrict__ tok,
                                                      float* __restrict__ out_total) {
    __shared__ int s_cs[TT];
    const int b = blockIdx.y;
    const int tid = threadIdx.x;
    const int total = block_scan_1024(dur, b, s_cs);
    if (blockIdx.x == 0 && tid == 0) out_total[b] = (float)total;

    const int f = blockIdx.x * 1024 + tid;
    uint16_t t = 0xFFFFu;
    if (f < total) {
        int lo = 0, hi = TT;
        while (lo < hi) {
            int mid = (lo + hi) >> 1;
            if (s_cs[mid] <= f) lo = mid + 1; else hi = mid;
        }
        t = (uint16_t)min(lo, TT - 1);
    }
    tok[b * MAXMEL + f] = t;
}

// 512 threads = 16 frames x 32 lanes; 3 float4 ld + 3 nt float4 st per thread.
__global__ __launch_bounds__(512) void lr_expand_tok16(const float* __restrict__ x,
                                                       const uint16_t* __restrict__ tok,
                                                       float* __restrict__ out) {
    const int b = blockIdx.y;
    const int frame = blockIdx.x * 16 + (threadIdx.x >> 5);
    const int lane = threadIdx.x & 31;
    const uint32_t t = tok[b * MAXMEL + frame];
    f4* outp = (f4*)(out + ((size_t)b * MAXMEL + frame) * CC);
    if (t != 0xFFFFu) {
        const f4* src = (const f4*)(x + ((size_t)b * TT + t) * CC);
        #pragma unroll
        for (int k = 0; k < 3; ++k) {
            f4 v = src[lane + k * 32];
            __builtin_nontemporal_store(v, &outp[lane + k * 32]);
        }
    } else {
        const f4 z = {0.f, 0.f, 0.f, 0.f};
        #pragma unroll
        for (int k = 0; k < 3; ++k) __builtin_nontemporal_store(z, &outp[lane + k * 32]);
    }
}

// ---------- Path B: cs only (128 KB ws, proven safe) + staged LDS search ----------

__global__ __launch_bounds__(1024) void lr_scan_cs(const int* __restrict__ dur,
                                                   int* __restrict__ cs,
                                                   float* __restrict__ out_total) {
    __shared__ int s_cs[TT];
    const int b = blockIdx.x;
    const int tid = threadIdx.x;
    const int total = block_scan_1024(dur, b, s_cs);
    cs[b * TT + tid] = s_cs[tid];
    if (tid == 0) out_total[b] = (float)total;
}

// 1024 threads = 64 frames x 16 lanes; 6 float4 per lane; cs staged once/block.
__global__ __launch_bounds__(1024) void lr_expand_search(const float* __restrict__ x,
                                                         const int* __restrict__ cs,
                                                         float* __restrict__ out) {
    __shared__ int s_cs[TT];
    const int b = blockIdx.y;
    const int tid = threadIdx.x;
    s_cs[tid] = cs[b * TT + tid];
    __syncthreads();
    const int total = s_cs[TT - 1];
    const int frame = blockIdx.x * 64 + (tid >> 4);
    const int lane = tid & 15;
    f4* outp = (f4*)(out + ((size_t)b * MAXMEL + frame) * CC);
    if (frame < total) {
        int lo = 0, hi = TT;
        while (lo < hi) {
            int mid = (lo + hi) >> 1;
            if (s_cs[mid] <= frame) lo = mid + 1; else hi = mid;
        }
        const int t = min(lo, TT - 1);
        const f4* src = (const f4*)(x + ((size_t)b * TT + t) * CC);
        #pragma unroll
        for (int k = 0; k < 6; ++k) outp[lane + k * 16] = src[lane + k * 16];
    } else {
        const f4 z = {0.f, 0.f, 0.f, 0.f};
        #pragma unroll
        for (int k = 0; k < 6; ++k) outp[lane + k * 16] = z;
    }
}

extern "C" void kernel_launch(void* const* d_in, const int* in_sizes, int n_in,
                              void* d_out, int out_size, void* d_ws, size_t ws_size,
                              hipStream_t stream) {
    const float* x = (const float*)d_in[0];
    const int* dur = (const int*)d_in[1];  // reference int64 -> int32 on device per harness
    float* out = (float*)d_out;
    float* out_total = out + (size_t)BB * MAXMEL * CC;  // 32 floats at the tail

    if (ws_size >= (size_t)BB * MAXMEL * sizeof(uint16_t)) {
        uint16_t* tok = (uint16_t*)d_ws;  // 256 KB
        lr_scan_tok16<<<dim3(4, BB), 1024, 0, stream>>>(dur, tok, out_total);
        lr_expand_tok16<<<dim3(MAXMEL / 16, BB), 512, 0, stream>>>(x, tok, out);
    } else {
        int* cs = (int*)d_ws;  // 128 KB
        lr_scan_cs<<<BB, 1024, 0, stream>>>(dur, cs, out_total);
        lr_expand_search<<<dim3(MAXMEL / 64, BB), 1024, 0, stream>>>(x, cs, out);
    }
}